// Round 2
// baseline (166.209 us; speedup 1.0000x reference)
//
#include <hip/hip_runtime.h>

// Problem constants (fixed by reference setup): B=8, X=Y=Z=128, P=64.
#define BATCH     8
#define DIM       128
#define NVOX      (BATCH * DIM * DIM * DIM)       // 16,777,216 floats
#define NPERSON   64
#define THREADS   256
#define FLOATS_PER_BLOCK 8192                     // 2048 float4
#define NBLOCK1   (NVOX / FLOATS_PER_BLOCK)       // 2048 sumsq blocks (256/batch)
#define TSIZE     4096
#define EMPTYK    0xFFFFFFFFu

// d_ws float layout:
//   [0..2047]    per-block sumsq partials
//   [2048..2055] sDil per batch
//   [2056..2063] sCorr per batch
//   [2064..2071] sPos per batch
//   [2072..2079] nr_persons per batch (as float)
//   [2080]       arrival counter (uint, zeroed by memset node each launch)
#define WS_DIL   2048
#define WS_CORR  2056
#define WS_POS   2064
#define WS_NR    2072
#define WS_CNT   2080

__global__ __launch_bounds__(THREADS) void person_loss_fused(
    const float* __restrict__ feature,
    const float* __restrict__ batch_index,
    const float* __restrict__ person_pos,
    const float* __restrict__ min_loc,
    const float* __restrict__ delta,
    float* __restrict__ ws,
    float* __restrict__ out)
{
    __shared__ unsigned keys[NPERSON];
    __shared__ int      uniq[NPERSON];
    __shared__ float    lDil[BATCH], lCorr[BATCH], lPos[BATCH];
    __shared__ int      lNr[BATCH];
    __shared__ unsigned table[TSIZE];
    __shared__ float    red[4];
    __shared__ float    sS2[BATCH];
    __shared__ int      isFinal;

    const int tid  = threadIdx.x;
    const int bid  = blockIdx.x;
    const int lane = tid & 63, wave = tid >> 6;
    unsigned* counter = (unsigned*)(ws + WS_CNT);

    if (bid < NBLOCK1) {
        // ---------------- dense path: partial sum of feature^2 ----------------
        const float4* f4 = (const float4*)feature;
        const size_t base = (size_t)bid * (FLOATS_PER_BLOCK / 4);
        float acc = 0.f;
#pragma unroll
        for (int j = 0; j < 8; ++j) {
            float4 v = f4[base + (size_t)j * THREADS + tid];
            acc += v.x * v.x + v.y * v.y + v.z * v.z + v.w * v.w;
        }
        for (int off = 32; off > 0; off >>= 1) acc += __shfl_down(acc, off, 64);
        if (lane == 0) red[wave] = acc;
        __syncthreads();
        if (tid == 0) ws[bid] = red[0] + red[1] + red[2] + red[3];
    } else {
        // ---------------- sparse path: persons / dilation ----------------
        if (tid < BATCH) { lDil[tid] = 0.f; lCorr[tid] = 0.f; lPos[tid] = 0.f; lNr[tid] = 0; }
        for (int s = tid; s < TSIZE; s += THREADS) table[s] = EMPTYK;

        if (tid < NPERSON) {
            const int p = tid;
            const int b = (int)(batch_index[p] + 0.5f);
            float vx = (person_pos[p * 3 + 0] - min_loc[0]) / delta[0];
            float vy = (person_pos[p * 3 + 1] - min_loc[1]) / delta[1];
            float vz = (person_pos[p * 3 + 2] - min_loc[2]) / delta[2];
            vx = fminf(fmaxf(vx, 0.f), (float)(DIM - 1));
            vy = fminf(fmaxf(vy, 0.f), (float)(DIM - 1));
            vz = fminf(fmaxf(vz, 0.f), (float)(DIM - 1));
            const int x = (int)(vx + 0.5f);
            const int y = (int)(vy + 0.5f);
            const int z = (int)(vz + 0.5f);
            keys[p] = ((unsigned)b << 21) | ((unsigned)x << 14) | ((unsigned)y << 7) | (unsigned)z;
        }
        __syncthreads();

        if (tid < NPERSON) {
            int u = 1;
            for (int q = 0; q < tid; ++q)
                if (keys[q] == keys[tid]) { u = 0; break; }
            uniq[tid] = u;
            if (u) atomicAdd(&lNr[keys[tid] >> 21], 1);
        }
        __syncthreads();

        for (int w = tid; w < NPERSON * 27; w += THREADS) {
            const int p = w / 27;
            if (!uniq[p]) continue;
            const unsigned k = keys[p];
            const int o = w % 27;
            const int x = (int)((k >> 14) & 127) + (o / 9) - 1;
            const int y = (int)((k >> 7) & 127) + ((o / 3) % 3) - 1;
            const int z = (int)(k & 127) + (o % 3) - 1;
            if ((unsigned)x > (unsigned)(DIM - 1) || (unsigned)y > (unsigned)(DIM - 1) ||
                (unsigned)z > (unsigned)(DIM - 1)) continue;
            const unsigned nk = (k & (7u << 21)) | ((unsigned)x << 14) | ((unsigned)y << 7) | (unsigned)z;
            unsigned h = ((nk * 2654435761u) >> 16) & (TSIZE - 1);
            for (;;) {
                const unsigned old = atomicCAS(&table[h], EMPTYK, nk);
                if (old == EMPTYK || old == nk) break;
                h = (h + 1) & (TSIZE - 1);
            }
        }
        __syncthreads();

        // Sdil[b] = sum over dilated voxels of (f - heat)^2
        for (int s = tid; s < TSIZE; s += THREADS) {
            const unsigned k = table[s];
            if (k == EMPTYK) continue;
            const int b = k >> 21;
            const int x = (k >> 14) & 127, y = (k >> 7) & 127, z = k & 127;
            const float f = feature[(((size_t)b * DIM + x) * DIM + y) * DIM + z];
            float heat = 0.f;
            for (int q = 0; q < NPERSON; ++q)
                if (keys[q] == k) { heat = 1.f; break; }
            const float d = f - heat;
            atomicAdd(&lDil[b], d * d);
        }

        // heat-voxel sums: Scorr = sum(1-2f), Spos = sum((f-1)^2)
        if (tid < NPERSON && uniq[tid]) {
            const unsigned k = keys[tid];
            const int b = k >> 21;
            const int x = (k >> 14) & 127, y = (k >> 7) & 127, z = k & 127;
            const float f = feature[(((size_t)b * DIM + x) * DIM + y) * DIM + z];
            atomicAdd(&lCorr[b], 1.f - 2.f * f);
            const float d = f - 1.f;
            atomicAdd(&lPos[b], d * d);
        }
        __syncthreads();

        if (tid == 0) {
#pragma unroll
            for (int b = 0; b < BATCH; ++b) {
                ws[WS_DIL  + b] = lDil[b];
                ws[WS_CORR + b] = lCorr[b];
                ws[WS_POS  + b] = lPos[b];
                ws[WS_NR   + b] = (float)lNr[b];
            }
        }
    }

    // ---------------- arrival + last-block finalize ----------------
    if (tid == 0) {
        __threadfence();                              // make this block's ws stores visible
        const unsigned old = atomicAdd(counter, 1u);  // device-scope
        isFinal = (old == (unsigned)NBLOCK1);         // last of NBLOCK1+1 blocks
    }
    __syncthreads();
    if (!isFinal) return;

    __threadfence();  // acquire: see all other blocks' ws stores
    for (int b = 0; b < BATCH; ++b) {
        float v = ws[b * (NBLOCK1 / BATCH) + tid];
        for (int off = 32; off > 0; off >>= 1) v += __shfl_down(v, off, 64);
        if (lane == 0) red[wave] = v;
        __syncthreads();
        if (tid == 0) sS2[b] = red[0] + red[1] + red[2] + red[3];
        __syncthreads();
    }

    if (tid < BATCH) {
        const int b = tid;
        const float nr = ws[WS_NR + b];
        const float N = (float)(DIM * DIM * DIM);
        const float scale_neg = nr * 27.f / N;
        const float scale_pos = 1.f - nr / N;
        const float neg = sS2[b] + ws[WS_CORR + b] - ws[WS_DIL + b];
        out[b] = (scale_neg * neg + scale_pos * ws[WS_POS + b]) / nr;
    }
}

extern "C" void kernel_launch(void* const* d_in, const int* in_sizes, int n_in,
                              void* d_out, int out_size, void* d_ws, size_t ws_size,
                              hipStream_t stream)
{
    const float* feature     = (const float*)d_in[0];
    const float* batch_index = (const float*)d_in[1];
    const float* person_pos  = (const float*)d_in[2];
    const float* min_loc     = (const float*)d_in[3];
    const float* delta       = (const float*)d_in[4];
    float* out = (float*)d_out;
    float* ws  = (float*)d_ws;

    // zero only the arrival counter (4 bytes); partials & sparse sums are
    // written unconditionally each launch, so 0xAA poison elsewhere is fine.
    hipMemsetAsync((char*)d_ws + WS_CNT * sizeof(float), 0, sizeof(unsigned), stream);

    person_loss_fused<<<NBLOCK1 + 1, THREADS, 0, stream>>>(
        feature, batch_index, person_pos, min_loc, delta, ws, out);
}

// Round 3
// 153.005 us; speedup vs baseline: 1.0863x; 1.0863x over previous
//
#include <hip/hip_runtime.h>

// Problem constants (fixed by reference setup): B=8, X=Y=Z=128, P=64.
#define BATCH     8
#define DIM       128
#define NVOX      (BATCH * DIM * DIM * DIM)       // 16,777,216 floats
#define NPERSON   64
#define THREADS   256
#define FLOATS_PER_BLOCK 8192                     // 2048 float4
#define NBLOCK1   (NVOX / FLOATS_PER_BLOCK)       // 2048 dense blocks (256/batch)
#define TSIZE     4096
#define EMPTYK    0xFFFFFFFFu

// d_ws float layout (all handoff via device-scope atomics at LLC; zeroed by
// one 168-byte memset node each launch):
//   [0]      arrival counter (uint)
//   [1..8]   sum(f^2) per batch
//   [9..16]  Sdil per batch
//   [17..24] Scorr per batch
//   [25..32] Spos per batch
//   [33..40] nr_persons per batch (as float)
#define WS_CNT   0
#define WS_S2    1
#define WS_DIL   9
#define WS_CORR  17
#define WS_POS   25
#define WS_NR    33
#define WS_ZERO_BYTES (41 * 4)

__global__ __launch_bounds__(THREADS) void person_loss_fused(
    const float* __restrict__ feature,
    const float* __restrict__ batch_index,
    const float* __restrict__ person_pos,
    const float* __restrict__ min_loc,
    const float* __restrict__ delta,
    float* __restrict__ ws,
    float* __restrict__ out)
{
    __shared__ unsigned keys[NPERSON];
    __shared__ int      uniq[NPERSON];
    __shared__ float    lDil[BATCH], lCorr[BATCH], lPos[BATCH];
    __shared__ int      lNr[BATCH];
    __shared__ unsigned table[TSIZE];
    __shared__ float    red[4];
    __shared__ int      isFinal;

    const int tid  = threadIdx.x;
    const int bid  = blockIdx.x;
    const int lane = tid & 63, wave = tid >> 6;
    unsigned* counter = (unsigned*)(ws + WS_CNT);

    if (bid < NBLOCK1) {
        // ---------------- dense path: partial sum of feature^2 ----------------
        const float4* f4 = (const float4*)feature;
        const size_t base = (size_t)bid * (FLOATS_PER_BLOCK / 4);
        float acc = 0.f;
#pragma unroll
        for (int j = 0; j < 8; ++j) {
            float4 v = f4[base + (size_t)j * THREADS + tid];
            acc += v.x * v.x + v.y * v.y + v.z * v.z + v.w * v.w;
        }
        for (int off = 32; off > 0; off >>= 1) acc += __shfl_down(acc, off, 64);
        if (lane == 0) red[wave] = acc;
        __syncthreads();
        if (tid == 0) {
            const float part = red[0] + red[1] + red[2] + red[3];
            // returning atomic -> completes at LLC before return value exists
            float old = atomicAdd(&ws[WS_S2 + (bid >> 8)], part);
            __asm__ volatile("" : "+v"(old) :: "memory");   // order before counter
            const unsigned prev = atomicAdd(counter, 1u);
            isFinal = (prev == (unsigned)NBLOCK1);          // last of NBLOCK1+1
        }
        __syncthreads();
    } else {
        // ---------------- sparse path: persons / dilation ----------------
        if (tid < BATCH) { lDil[tid] = 0.f; lCorr[tid] = 0.f; lPos[tid] = 0.f; lNr[tid] = 0; }
        for (int s = tid; s < TSIZE; s += THREADS) table[s] = EMPTYK;

        if (tid < NPERSON) {
            const int p = tid;
            const int b = (int)(batch_index[p] + 0.5f);
            float vx = (person_pos[p * 3 + 0] - min_loc[0]) / delta[0];
            float vy = (person_pos[p * 3 + 1] - min_loc[1]) / delta[1];
            float vz = (person_pos[p * 3 + 2] - min_loc[2]) / delta[2];
            vx = fminf(fmaxf(vx, 0.f), (float)(DIM - 1));
            vy = fminf(fmaxf(vy, 0.f), (float)(DIM - 1));
            vz = fminf(fmaxf(vz, 0.f), (float)(DIM - 1));
            const int x = (int)(vx + 0.5f);
            const int y = (int)(vy + 0.5f);
            const int z = (int)(vz + 0.5f);
            keys[p] = ((unsigned)b << 21) | ((unsigned)x << 14) | ((unsigned)y << 7) | (unsigned)z;
        }
        __syncthreads();

        if (tid < NPERSON) {
            int u = 1;
            for (int q = 0; q < tid; ++q)
                if (keys[q] == keys[tid]) { u = 0; break; }
            uniq[tid] = u;
            if (u) atomicAdd(&lNr[keys[tid] >> 21], 1);
        }
        __syncthreads();

        for (int w = tid; w < NPERSON * 27; w += THREADS) {
            const int p = w / 27;
            if (!uniq[p]) continue;
            const unsigned k = keys[p];
            const int o = w % 27;
            const int x = (int)((k >> 14) & 127) + (o / 9) - 1;
            const int y = (int)((k >> 7) & 127) + ((o / 3) % 3) - 1;
            const int z = (int)(k & 127) + (o % 3) - 1;
            if ((unsigned)x > (unsigned)(DIM - 1) || (unsigned)y > (unsigned)(DIM - 1) ||
                (unsigned)z > (unsigned)(DIM - 1)) continue;
            const unsigned nk = (k & (7u << 21)) | ((unsigned)x << 14) | ((unsigned)y << 7) | (unsigned)z;
            unsigned h = ((nk * 2654435761u) >> 16) & (TSIZE - 1);
            for (;;) {
                const unsigned old = atomicCAS(&table[h], EMPTYK, nk);
                if (old == EMPTYK || old == nk) break;
                h = (h + 1) & (TSIZE - 1);
            }
        }
        __syncthreads();

        // Sdil[b] = sum over dilated voxels of (f - heat)^2
        for (int s = tid; s < TSIZE; s += THREADS) {
            const unsigned k = table[s];
            if (k == EMPTYK) continue;
            const int b = k >> 21;
            const int x = (k >> 14) & 127, y = (k >> 7) & 127, z = k & 127;
            const float f = feature[(((size_t)b * DIM + x) * DIM + y) * DIM + z];
            float heat = 0.f;
            for (int q = 0; q < NPERSON; ++q)
                if (keys[q] == k) { heat = 1.f; break; }
            const float d = f - heat;
            atomicAdd(&lDil[b], d * d);
        }

        // heat-voxel sums: Scorr = sum(1-2f), Spos = sum((f-1)^2)
        if (tid < NPERSON && uniq[tid]) {
            const unsigned k = keys[tid];
            const int b = k >> 21;
            const int x = (k >> 14) & 127, y = (k >> 7) & 127, z = k & 127;
            const float f = feature[(((size_t)b * DIM + x) * DIM + y) * DIM + z];
            atomicAdd(&lCorr[b], 1.f - 2.f * f);
            const float d = f - 1.f;
            atomicAdd(&lPos[b], d * d);
        }
        __syncthreads();

        // flush per-batch sums to LLC accumulators (returning atomics so each
        // is complete before its thread reaches the barrier)
        if (tid < BATCH) {
            float o0 = atomicAdd(&ws[WS_DIL  + tid], lDil[tid]);
            float o1 = atomicAdd(&ws[WS_CORR + tid], lCorr[tid]);
            float o2 = atomicAdd(&ws[WS_POS  + tid], lPos[tid]);
            float o3 = atomicAdd(&ws[WS_NR   + tid], (float)lNr[tid]);
            __asm__ volatile("" : "+v"(o0), "+v"(o1), "+v"(o2), "+v"(o3) :: "memory");
        }
        __syncthreads();
        if (tid == 0) {
            const unsigned prev = atomicAdd(counter, 1u);
            isFinal = (prev == (unsigned)NBLOCK1);
        }
        __syncthreads();
    }

    // ---------------- last-arriving block: final combine ----------------
    if (!isFinal) return;

    if (tid < BATCH) {
        const int b = tid;
        // returning atomics read fresh LLC values (no fence/invalidate needed)
        const float s2   = atomicAdd(&ws[WS_S2   + b], 0.f);
        const float dil  = atomicAdd(&ws[WS_DIL  + b], 0.f);
        const float corr = atomicAdd(&ws[WS_CORR + b], 0.f);
        const float pos  = atomicAdd(&ws[WS_POS  + b], 0.f);
        const float nr   = atomicAdd(&ws[WS_NR   + b], 0.f);
        const float N = (float)(DIM * DIM * DIM);
        const float scale_neg = nr * 27.f / N;
        const float scale_pos = 1.f - nr / N;
        const float neg = s2 + corr - dil;
        out[b] = (scale_neg * neg + scale_pos * pos) / nr;
    }
}

extern "C" void kernel_launch(void* const* d_in, const int* in_sizes, int n_in,
                              void* d_out, int out_size, void* d_ws, size_t ws_size,
                              hipStream_t stream)
{
    const float* feature     = (const float*)d_in[0];
    const float* batch_index = (const float*)d_in[1];
    const float* person_pos  = (const float*)d_in[2];
    const float* min_loc     = (const float*)d_in[3];
    const float* delta       = (const float*)d_in[4];
    float* out = (float*)d_out;
    float* ws  = (float*)d_ws;

    // zero counter + 40 accumulator floats (168 B); rest of ws unused
    hipMemsetAsync(d_ws, 0, WS_ZERO_BYTES, stream);

    person_loss_fused<<<NBLOCK1 + 1, THREADS, 0, stream>>>(
        feature, batch_index, person_pos, min_loc, delta, ws, out);
}

// Round 4
// 117.917 us; speedup vs baseline: 1.4095x; 1.2976x over previous
//
#include <hip/hip_runtime.h>

// Problem constants (fixed by reference setup): B=8, X=Y=Z=128, P=64.
#define BATCH     8
#define DIM       128
#define NVOX      (BATCH * DIM * DIM * DIM)       // 16,777,216 floats
#define NPERSON   64
#define THREADS   256
#define FLOATS_PER_BLOCK 8192                     // 2048 float4
#define NBLOCK1   (NVOX / FLOATS_PER_BLOCK)       // 2048 dense blocks (256/batch)
#define TSIZE     4096
#define EMPTYK    0xFFFFFFFFu

// d_ws float layout (all plain stores; coherence via kernel boundary):
//   [0..2047]    per-block sumsq partials (batch b owns [b*256, b*256+256))
//   [2048..2055] Sdil per batch
//   [2056..2063] Scorr per batch
//   [2064..2071] Spos per batch
//   [2072..2079] nr_persons per batch (as float)
// No zeroing needed: every slot read by kernel B is written unconditionally
// by kernel A each launch (0xAA re-poison safe).
#define WS_DIL   2048
#define WS_CORR  2056
#define WS_POS   2064
#define WS_NR    2072

// ---------------------------------------------------------------------------
// Kernel A: dense sumsq sweep (blocks 0..2047) + concurrent sparse block (2048).
// No atomics to global, no fences — handoff is plain stores + kernel boundary.
// ---------------------------------------------------------------------------
__global__ __launch_bounds__(THREADS) void person_loss_main(
    const float* __restrict__ feature,
    const float* __restrict__ batch_index,
    const float* __restrict__ person_pos,
    const float* __restrict__ min_loc,
    const float* __restrict__ delta,
    float* __restrict__ ws)
{
    __shared__ unsigned keys[NPERSON];
    __shared__ int      uniq[NPERSON];
    __shared__ float    lDil[BATCH], lCorr[BATCH], lPos[BATCH];
    __shared__ int      lNr[BATCH];
    __shared__ unsigned table[TSIZE];
    __shared__ float    red[4];

    const int tid  = threadIdx.x;
    const int bid  = blockIdx.x;
    const int lane = tid & 63, wave = tid >> 6;

    if (bid < NBLOCK1) {
        // ---------------- dense path: partial sum of feature^2 ----------------
        const float4* f4 = (const float4*)feature;
        const size_t base = (size_t)bid * (FLOATS_PER_BLOCK / 4);
        float acc = 0.f;
#pragma unroll
        for (int j = 0; j < 8; ++j) {
            float4 v = f4[base + (size_t)j * THREADS + tid];
            acc += v.x * v.x + v.y * v.y + v.z * v.z + v.w * v.w;
        }
        for (int off = 32; off > 0; off >>= 1) acc += __shfl_down(acc, off, 64);
        if (lane == 0) red[wave] = acc;
        __syncthreads();
        if (tid == 0) ws[bid] = red[0] + red[1] + red[2] + red[3];
        return;
    }

    // ---------------- sparse path: persons / dilation (block 2048) ----------------
    if (tid < BATCH) { lDil[tid] = 0.f; lCorr[tid] = 0.f; lPos[tid] = 0.f; lNr[tid] = 0; }
    for (int s = tid; s < TSIZE; s += THREADS) table[s] = EMPTYK;

    if (tid < NPERSON) {
        const int p = tid;
        const int b = (int)(batch_index[p] + 0.5f);
        float vx = (person_pos[p * 3 + 0] - min_loc[0]) / delta[0];
        float vy = (person_pos[p * 3 + 1] - min_loc[1]) / delta[1];
        float vz = (person_pos[p * 3 + 2] - min_loc[2]) / delta[2];
        vx = fminf(fmaxf(vx, 0.f), (float)(DIM - 1));
        vy = fminf(fmaxf(vy, 0.f), (float)(DIM - 1));
        vz = fminf(fmaxf(vz, 0.f), (float)(DIM - 1));
        const int x = (int)(vx + 0.5f);
        const int y = (int)(vy + 0.5f);
        const int z = (int)(vz + 0.5f);
        keys[p] = ((unsigned)b << 21) | ((unsigned)x << 14) | ((unsigned)y << 7) | (unsigned)z;
    }
    __syncthreads();

    // dedup persons; nr_persons[b] counts distinct voxels
    if (tid < NPERSON) {
        int u = 1;
        for (int q = 0; q < tid; ++q)
            if (keys[q] == keys[tid]) { u = 0; break; }
        uniq[tid] = u;
        if (u) atomicAdd(&lNr[keys[tid] >> 21], 1);   // LDS atomic only
    }
    __syncthreads();

    // insert 3x3x3 dilation neighborhood into LDS hash (dedup via CAS)
    for (int w = tid; w < NPERSON * 27; w += THREADS) {
        const int p = w / 27;
        if (!uniq[p]) continue;
        const unsigned k = keys[p];
        const int o = w % 27;
        const int x = (int)((k >> 14) & 127) + (o / 9) - 1;
        const int y = (int)((k >> 7) & 127) + ((o / 3) % 3) - 1;
        const int z = (int)(k & 127) + (o % 3) - 1;
        if ((unsigned)x > (unsigned)(DIM - 1) || (unsigned)y > (unsigned)(DIM - 1) ||
            (unsigned)z > (unsigned)(DIM - 1)) continue;
        const unsigned nk = (k & (7u << 21)) | ((unsigned)x << 14) | ((unsigned)y << 7) | (unsigned)z;
        unsigned h = ((nk * 2654435761u) >> 16) & (TSIZE - 1);
        for (;;) {
            const unsigned old = atomicCAS(&table[h], EMPTYK, nk);
            if (old == EMPTYK || old == nk) break;
            h = (h + 1) & (TSIZE - 1);
        }
    }
    __syncthreads();

    // Sdil[b] = sum over dilated voxels of (f - heat)^2
    for (int s = tid; s < TSIZE; s += THREADS) {
        const unsigned k = table[s];
        if (k == EMPTYK) continue;
        const int b = k >> 21;
        const int x = (k >> 14) & 127, y = (k >> 7) & 127, z = k & 127;
        const float f = feature[(((size_t)b * DIM + x) * DIM + y) * DIM + z];
        float heat = 0.f;
        for (int q = 0; q < NPERSON; ++q)
            if (keys[q] == k) { heat = 1.f; break; }
        const float d = f - heat;
        atomicAdd(&lDil[b], d * d);   // LDS atomic only
    }

    // heat-voxel sums: Scorr = sum(1-2f), Spos = sum((f-1)^2)
    if (tid < NPERSON && uniq[tid]) {
        const unsigned k = keys[tid];
        const int b = k >> 21;
        const int x = (k >> 14) & 127, y = (k >> 7) & 127, z = k & 127;
        const float f = feature[(((size_t)b * DIM + x) * DIM + y) * DIM + z];
        atomicAdd(&lCorr[b], 1.f - 2.f * f);
        const float d = f - 1.f;
        atomicAdd(&lPos[b], d * d);
    }
    __syncthreads();

    if (tid < BATCH) {
        ws[WS_DIL  + tid] = lDil[tid];
        ws[WS_CORR + tid] = lCorr[tid];
        ws[WS_POS  + tid] = lPos[tid];
        ws[WS_NR   + tid] = (float)lNr[tid];
    }
}

// ---------------------------------------------------------------------------
// Kernel B: single tiny block — reduce 2048 partials, combine, emit 8 losses.
// ---------------------------------------------------------------------------
__global__ __launch_bounds__(THREADS) void person_loss_combine(
    const float* __restrict__ ws, float* __restrict__ out)
{
    __shared__ float red[4];
    __shared__ float sS2[BATCH];
    const int tid = threadIdx.x;
    const int lane = tid & 63, wave = tid >> 6;

    for (int b = 0; b < BATCH; ++b) {
        float v = ws[b * (NBLOCK1 / BATCH) + tid];
        for (int off = 32; off > 0; off >>= 1) v += __shfl_down(v, off, 64);
        if (lane == 0) red[wave] = v;
        __syncthreads();
        if (tid == 0) sS2[b] = red[0] + red[1] + red[2] + red[3];
        __syncthreads();
    }

    if (tid < BATCH) {
        const int b = tid;
        const float nr = ws[WS_NR + b];
        const float N = (float)(DIM * DIM * DIM);
        const float scale_neg = nr * 27.f / N;
        const float scale_pos = 1.f - nr / N;
        const float neg = sS2[b] + ws[WS_CORR + b] - ws[WS_DIL + b];
        out[b] = (scale_neg * neg + scale_pos * ws[WS_POS + b]) / nr;
    }
}

extern "C" void kernel_launch(void* const* d_in, const int* in_sizes, int n_in,
                              void* d_out, int out_size, void* d_ws, size_t ws_size,
                              hipStream_t stream)
{
    const float* feature     = (const float*)d_in[0];
    const float* batch_index = (const float*)d_in[1];
    const float* person_pos  = (const float*)d_in[2];
    const float* min_loc     = (const float*)d_in[3];
    const float* delta       = (const float*)d_in[4];
    float* out = (float*)d_out;
    float* ws  = (float*)d_ws;

    person_loss_main<<<NBLOCK1 + 1, THREADS, 0, stream>>>(
        feature, batch_index, person_pos, min_loc, delta, ws);
    person_loss_combine<<<1, THREADS, 0, stream>>>(ws, out);
}

// Round 5
// 102.471 us; speedup vs baseline: 1.6220x; 1.1507x over previous
//
#include <hip/hip_runtime.h>

// Problem constants (fixed by reference setup): B=8, X=Y=Z=128, P=64.
#define BATCH     8
#define DIM       128
#define NVOX      (BATCH * DIM * DIM * DIM)       // 16,777,216 floats
#define NPERSON   64
#define THREADS   256
#define FLOATS_PER_BLOCK 8192                     // 2048 float4
#define NBLOCK1   (NVOX / FLOATS_PER_BLOCK)       // 2048 dense blocks (256/batch)
#define TSIZE     4096
#define EMPTYK    0xFFFFFFFFu
#define KEYMASK   0x00FFFFFFu
#define HEATBIT   0x40000000u

// d_ws float layout (plain stores only; coherence via kernel boundary):
//   [0..2047]    per-block sumsq partials (batch b owns [b*256, b*256+256))
//   [2048..2055] Sdil per batch
//   [2056..2063] Scorr per batch
//   [2064..2071] Spos per batch
//   [2072..2079] nr_persons per batch (as float)
// No zeroing needed: every slot read by kernel B is written unconditionally.
#define WS_DIL   2048
#define WS_CORR  2056
#define WS_POS   2064
#define WS_NR    2072

// ---------------------------------------------------------------------------
// Kernel A: block 0 = sparse person/dilation work (latency-pipelined);
//           blocks 1..2048 = dense sumsq sweep. No global atomics/fences.
// ---------------------------------------------------------------------------
__global__ __launch_bounds__(THREADS) void person_loss_main(
    const float* __restrict__ feature,
    const float* __restrict__ batch_index,
    const float* __restrict__ person_pos,
    const float* __restrict__ min_loc,
    const float* __restrict__ delta,
    float* __restrict__ ws)
{
    __shared__ unsigned keys[NPERSON];
    __shared__ int      uniq[NPERSON];
    __shared__ float    lDil[BATCH], lCorr[BATCH], lPos[BATCH];
    __shared__ int      lNr[BATCH];
    __shared__ unsigned table[TSIZE];
    __shared__ float    red[4];

    const int tid  = threadIdx.x;
    const int bid  = blockIdx.x;
    const int lane = tid & 63, wave = tid >> 6;

    if (bid != 0) {
        // ---------------- dense path: partial sum of feature^2 ----------------
        const float4* f4 = (const float4*)feature;
        const size_t base = (size_t)(bid - 1) * (FLOATS_PER_BLOCK / 4);
        float acc = 0.f;
#pragma unroll
        for (int j = 0; j < 8; ++j) {
            float4 v = f4[base + (size_t)j * THREADS + tid];
            acc += v.x * v.x + v.y * v.y + v.z * v.z + v.w * v.w;
        }
        for (int off = 32; off > 0; off >>= 1) acc += __shfl_down(acc, off, 64);
        if (lane == 0) red[wave] = acc;
        __syncthreads();
        if (tid == 0) ws[bid - 1] = red[0] + red[1] + red[2] + red[3];
        return;
    }

    // ---------------- sparse path (block 0) ----------------
    if (tid < BATCH) { lDil[tid] = 0.f; lCorr[tid] = 0.f; lPos[tid] = 0.f; lNr[tid] = 0; }
    for (int s = tid; s < TSIZE; s += THREADS) table[s] = EMPTYK;

    if (tid < NPERSON) {
        const int p = tid;
        const int b = (int)(batch_index[p] + 0.5f);
        float vx = (person_pos[p * 3 + 0] - min_loc[0]) / delta[0];
        float vy = (person_pos[p * 3 + 1] - min_loc[1]) / delta[1];
        float vz = (person_pos[p * 3 + 2] - min_loc[2]) / delta[2];
        vx = fminf(fmaxf(vx, 0.f), (float)(DIM - 1));
        vy = fminf(fmaxf(vy, 0.f), (float)(DIM - 1));
        vz = fminf(fmaxf(vz, 0.f), (float)(DIM - 1));
        const int x = (int)(vx + 0.5f);
        const int y = (int)(vy + 0.5f);
        const int z = (int)(vz + 0.5f);
        keys[p] = ((unsigned)b << 21) | ((unsigned)x << 14) | ((unsigned)y << 7) | (unsigned)z;
    }
    __syncthreads();

    // dedup persons — fixed 64-trip loop (no break) so LDS reads pipeline
    if (tid < NPERSON) {
        const unsigned mykey = keys[tid];
        int u = 1;
#pragma unroll
        for (int q = 0; q < NPERSON; ++q) {
            if (q < tid && keys[q] == mykey) u = 0;
        }
        uniq[tid] = u;
        if (u) atomicAdd(&lNr[mykey >> 21], 1);   // LDS atomic
    }
    __syncthreads();

    // insert 3x3x3 dilation neighborhood into LDS hash (dedup via CAS)
    for (int w = tid; w < NPERSON * 27; w += THREADS) {
        const int p = w / 27;
        if (!uniq[p]) continue;
        const unsigned k = keys[p];
        const int o = w % 27;
        const int x = (int)((k >> 14) & 127) + (o / 9) - 1;
        const int y = (int)((k >> 7) & 127) + ((o / 3) % 3) - 1;
        const int z = (int)(k & 127) + (o % 3) - 1;
        if ((unsigned)x > (unsigned)(DIM - 1) || (unsigned)y > (unsigned)(DIM - 1) ||
            (unsigned)z > (unsigned)(DIM - 1)) continue;
        const unsigned nk = (k & (7u << 21)) | ((unsigned)x << 14) | ((unsigned)y << 7) | (unsigned)z;
        unsigned h = ((nk * 2654435761u) >> 16) & (TSIZE - 1);
        for (;;) {
            const unsigned old = atomicCAS(&table[h], EMPTYK, nk);
            if (old == EMPTYK || (old & KEYMASK) == nk) break;
            h = (h + 1) & (TSIZE - 1);
        }
    }
    __syncthreads();

    // mark heat voxels: each unique person ORs HEATBIT into its entry
    if (tid < NPERSON && uniq[tid]) {
        const unsigned k = keys[tid];
        unsigned h = ((k * 2654435761u) >> 16) & (TSIZE - 1);
        for (;;) {
            const unsigned e = table[h];
            if (e != EMPTYK && (e & KEYMASK) == k) { atomicOr(&table[h], HEATBIT); break; }
            h = (h + 1) & (TSIZE - 1);
        }
    }
    __syncthreads();

    // gather: two chunks of 8 slots/thread; entry reads and global loads are
    // hoisted & independent so each chunk pays ~one HBM latency total
#pragma unroll
    for (int c = 0; c < 2; ++c) {
        unsigned e[8];
#pragma unroll
        for (int j = 0; j < 8; ++j)
            e[j] = table[(c * 8 + j) * THREADS + tid];

        float f[8];
#pragma unroll
        for (int j = 0; j < 8; ++j) {
            f[j] = 0.f;
            if (e[j] != EMPTYK) {
                const unsigned k = e[j];
                const int b = (k >> 21) & 7;
                const int x = (k >> 14) & 127, y = (k >> 7) & 127, z = k & 127;
                f[j] = feature[(((size_t)b * DIM + x) * DIM + y) * DIM + z];
            }
        }
#pragma unroll
        for (int j = 0; j < 8; ++j) {
            if (e[j] == EMPTYK) continue;
            const int b = (e[j] >> 21) & 7;
            const float heat = (e[j] & HEATBIT) ? 1.f : 0.f;
            const float d = f[j] - heat;
            atomicAdd(&lDil[b], d * d);
            if (e[j] & HEATBIT) {
                atomicAdd(&lCorr[b], 1.f - 2.f * f[j]);
                const float dp = f[j] - 1.f;
                atomicAdd(&lPos[b], dp * dp);
            }
        }
    }
    __syncthreads();

    if (tid < BATCH) {
        ws[WS_DIL  + tid] = lDil[tid];
        ws[WS_CORR + tid] = lCorr[tid];
        ws[WS_POS  + tid] = lPos[tid];
        ws[WS_NR   + tid] = (float)lNr[tid];
    }
}

// ---------------------------------------------------------------------------
// Kernel B: single tiny block — reduce 2048 partials, combine, emit 8 losses.
// ---------------------------------------------------------------------------
__global__ __launch_bounds__(THREADS) void person_loss_combine(
    const float* __restrict__ ws, float* __restrict__ out)
{
    __shared__ float red[4];
    __shared__ float sS2[BATCH];
    const int tid = threadIdx.x;
    const int lane = tid & 63, wave = tid >> 6;

    for (int b = 0; b < BATCH; ++b) {
        float v = ws[b * (NBLOCK1 / BATCH) + tid];
        for (int off = 32; off > 0; off >>= 1) v += __shfl_down(v, off, 64);
        if (lane == 0) red[wave] = v;
        __syncthreads();
        if (tid == 0) sS2[b] = red[0] + red[1] + red[2] + red[3];
        __syncthreads();
    }

    if (tid < BATCH) {
        const int b = tid;
        const float nr = ws[WS_NR + b];
        const float N = (float)(DIM * DIM * DIM);
        const float scale_neg = nr * 27.f / N;
        const float scale_pos = 1.f - nr / N;
        const float neg = sS2[b] + ws[WS_CORR + b] - ws[WS_DIL + b];
        out[b] = (scale_neg * neg + scale_pos * ws[WS_POS + b]) / nr;
    }
}

extern "C" void kernel_launch(void* const* d_in, const int* in_sizes, int n_in,
                              void* d_out, int out_size, void* d_ws, size_t ws_size,
                              hipStream_t stream)
{
    const float* feature     = (const float*)d_in[0];
    const float* batch_index = (const float*)d_in[1];
    const float* person_pos  = (const float*)d_in[2];
    const float* min_loc     = (const float*)d_in[3];
    const float* delta       = (const float*)d_in[4];
    float* out = (float*)d_out;
    float* ws  = (float*)d_ws;

    person_loss_main<<<NBLOCK1 + 1, THREADS, 0, stream>>>(
        feature, batch_index, person_pos, min_loc, delta, ws);
    person_loss_combine<<<1, THREADS, 0, stream>>>(ws, out);
}

// Round 6
// 101.487 us; speedup vs baseline: 1.6377x; 1.0097x over previous
//
#include <hip/hip_runtime.h>

// Problem constants (fixed by reference setup): B=8, X=Y=Z=128, P=64.
#define BATCH     8
#define DIM       128
#define NVOX      (BATCH * DIM * DIM * DIM)       // 16,777,216 floats
#define NPERSON   64
#define THREADS   256
#define FLOATS_PER_BLOCK 8192                     // 2048 float4
#define NBLOCK1   (NVOX / FLOATS_PER_BLOCK)       // 2048 dense blocks (256/batch)
#define TSIZE     4096
#define EMPTYK    0xFFFFFFFFu
#define KEYMASK   0x00FFFFFFu
#define HEATBIT   0x40000000u

// d_ws float layout (plain stores only; coherence via kernel boundary):
//   [0..2047]    per-block sumsq partials (batch b owns [b*256, b*256+256))
//   [2048..2055] Sdil per batch
//   [2056..2063] Scorr per batch
//   [2064..2071] Spos per batch
//   [2072..2079] nr_persons per batch (as float)
// No zeroing needed: every slot read by kernel B is written unconditionally.
#define WS_DIL   2048
#define WS_CORR  2056
#define WS_POS   2064
#define WS_NR    2072

// ---------------------------------------------------------------------------
// Kernel A: block 0 = sparse person/dilation work (latency-pipelined);
//           blocks 1..2048 = dense sumsq sweep. No global atomics/fences.
// ---------------------------------------------------------------------------
__global__ __launch_bounds__(THREADS) void person_loss_main(
    const float* __restrict__ feature,
    const float* __restrict__ batch_index,
    const float* __restrict__ person_pos,
    const float* __restrict__ min_loc,
    const float* __restrict__ delta,
    float* __restrict__ ws)
{
    __shared__ unsigned keys[NPERSON];
    __shared__ int      uniq[NPERSON];
    __shared__ float    lDil[BATCH], lCorr[BATCH], lPos[BATCH];
    __shared__ int      lNr[BATCH];
    __shared__ unsigned table[TSIZE];
    __shared__ float    red[4];

    const int tid  = threadIdx.x;
    const int bid  = blockIdx.x;
    const int lane = tid & 63, wave = tid >> 6;

    if (bid != 0) {
        // ---------------- dense path: partial sum of feature^2 ----------------
        const float4* f4 = (const float4*)feature;
        const size_t base = (size_t)(bid - 1) * (FLOATS_PER_BLOCK / 4);
        float acc = 0.f;
#pragma unroll
        for (int j = 0; j < 8; ++j) {
            float4 v = f4[base + (size_t)j * THREADS + tid];
            acc += v.x * v.x + v.y * v.y + v.z * v.z + v.w * v.w;
        }
        for (int off = 32; off > 0; off >>= 1) acc += __shfl_down(acc, off, 64);
        if (lane == 0) red[wave] = acc;
        __syncthreads();
        if (tid == 0) ws[bid - 1] = red[0] + red[1] + red[2] + red[3];
        return;
    }

    // ---------------- sparse path (block 0) ----------------
    if (tid < BATCH) { lDil[tid] = 0.f; lCorr[tid] = 0.f; lPos[tid] = 0.f; lNr[tid] = 0; }
    for (int s = tid; s < TSIZE; s += THREADS) table[s] = EMPTYK;

    if (tid < NPERSON) {
        const int p = tid;
        const int b = (int)(batch_index[p] + 0.5f);
        float vx = (person_pos[p * 3 + 0] - min_loc[0]) / delta[0];
        float vy = (person_pos[p * 3 + 1] - min_loc[1]) / delta[1];
        float vz = (person_pos[p * 3 + 2] - min_loc[2]) / delta[2];
        vx = fminf(fmaxf(vx, 0.f), (float)(DIM - 1));
        vy = fminf(fmaxf(vy, 0.f), (float)(DIM - 1));
        vz = fminf(fmaxf(vz, 0.f), (float)(DIM - 1));
        const int x = (int)(vx + 0.5f);
        const int y = (int)(vy + 0.5f);
        const int z = (int)(vz + 0.5f);
        keys[p] = ((unsigned)b << 21) | ((unsigned)x << 14) | ((unsigned)y << 7) | (unsigned)z;
    }
    __syncthreads();

    // dedup persons — fixed 64-trip loop (no break) so LDS reads pipeline
    if (tid < NPERSON) {
        const unsigned mykey = keys[tid];
        int u = 1;
#pragma unroll
        for (int q = 0; q < NPERSON; ++q) {
            if (q < tid && keys[q] == mykey) u = 0;
        }
        uniq[tid] = u;
        if (u) atomicAdd(&lNr[mykey >> 21], 1);   // LDS atomic
    }
    __syncthreads();

    // insert 3x3x3 dilation neighborhood into LDS hash (dedup via CAS)
    for (int w = tid; w < NPERSON * 27; w += THREADS) {
        const int p = w / 27;
        if (!uniq[p]) continue;
        const unsigned k = keys[p];
        const int o = w % 27;
        const int x = (int)((k >> 14) & 127) + (o / 9) - 1;
        const int y = (int)((k >> 7) & 127) + ((o / 3) % 3) - 1;
        const int z = (int)(k & 127) + (o % 3) - 1;
        if ((unsigned)x > (unsigned)(DIM - 1) || (unsigned)y > (unsigned)(DIM - 1) ||
            (unsigned)z > (unsigned)(DIM - 1)) continue;
        const unsigned nk = (k & (7u << 21)) | ((unsigned)x << 14) | ((unsigned)y << 7) | (unsigned)z;
        unsigned h = ((nk * 2654435761u) >> 16) & (TSIZE - 1);
        for (;;) {
            const unsigned old = atomicCAS(&table[h], EMPTYK, nk);
            if (old == EMPTYK || (old & KEYMASK) == nk) break;
            h = (h + 1) & (TSIZE - 1);
        }
    }
    __syncthreads();

    // mark heat voxels: each unique person ORs HEATBIT into its entry
    if (tid < NPERSON && uniq[tid]) {
        const unsigned k = keys[tid];
        unsigned h = ((k * 2654435761u) >> 16) & (TSIZE - 1);
        for (;;) {
            const unsigned e = table[h];
            if (e != EMPTYK && (e & KEYMASK) == k) { atomicOr(&table[h], HEATBIT); break; }
            h = (h + 1) & (TSIZE - 1);
        }
    }
    __syncthreads();

    // gather: two chunks of 8 slots/thread; entry reads and global loads are
    // hoisted & independent so each chunk pays ~one HBM latency total
#pragma unroll
    for (int c = 0; c < 2; ++c) {
        unsigned e[8];
#pragma unroll
        for (int j = 0; j < 8; ++j)
            e[j] = table[(c * 8 + j) * THREADS + tid];

        float f[8];
#pragma unroll
        for (int j = 0; j < 8; ++j) {
            f[j] = 0.f;
            if (e[j] != EMPTYK) {
                const unsigned k = e[j];
                const int b = (k >> 21) & 7;
                const int x = (k >> 14) & 127, y = (k >> 7) & 127, z = k & 127;
                f[j] = feature[(((size_t)b * DIM + x) * DIM + y) * DIM + z];
            }
        }
#pragma unroll
        for (int j = 0; j < 8; ++j) {
            if (e[j] == EMPTYK) continue;
            const int b = (e[j] >> 21) & 7;
            const float heat = (e[j] & HEATBIT) ? 1.f : 0.f;
            const float d = f[j] - heat;
            atomicAdd(&lDil[b], d * d);
            if (e[j] & HEATBIT) {
                atomicAdd(&lCorr[b], 1.f - 2.f * f[j]);
                const float dp = f[j] - 1.f;
                atomicAdd(&lPos[b], dp * dp);
            }
        }
    }
    __syncthreads();

    if (tid < BATCH) {
        ws[WS_DIL  + tid] = lDil[tid];
        ws[WS_CORR + tid] = lCorr[tid];
        ws[WS_POS  + tid] = lPos[tid];
        ws[WS_NR   + tid] = (float)lNr[tid];
    }
}

// ---------------------------------------------------------------------------
// Kernel B: single tiny block. All 8x256 partial loads issued up-front
// (independent -> one LLC latency), register wave-reduction, ONE barrier.
// ---------------------------------------------------------------------------
__global__ __launch_bounds__(THREADS) void person_loss_combine(
    const float* __restrict__ ws, float* __restrict__ out)
{
    __shared__ float red[BATCH][4];
    const int tid = threadIdx.x;
    const int lane = tid & 63, wave = tid >> 6;

    // 8 independent loads per thread (one per batch segment) + 4 tail floats
    float v[BATCH];
#pragma unroll
    for (int b = 0; b < BATCH; ++b) v[b] = ws[b * (NBLOCK1 / BATCH) + tid];

#pragma unroll
    for (int b = 0; b < BATCH; ++b) {
        float s = v[b];
        for (int off = 32; off > 0; off >>= 1) s += __shfl_down(s, off, 64);
        if (lane == 0) red[b][wave] = s;
    }
    __syncthreads();

    if (tid < BATCH) {
        const int b = tid;
        const float sS2 = red[b][0] + red[b][1] + red[b][2] + red[b][3];
        const float nr  = ws[WS_NR + b];
        const float N = (float)(DIM * DIM * DIM);
        const float scale_neg = nr * 27.f / N;
        const float scale_pos = 1.f - nr / N;
        const float neg = sS2 + ws[WS_CORR + b] - ws[WS_DIL + b];
        out[b] = (scale_neg * neg + scale_pos * ws[WS_POS + b]) / nr;
    }
}

extern "C" void kernel_launch(void* const* d_in, const int* in_sizes, int n_in,
                              void* d_out, int out_size, void* d_ws, size_t ws_size,
                              hipStream_t stream)
{
    const float* feature     = (const float*)d_in[0];
    const float* batch_index = (const float*)d_in[1];
    const float* person_pos  = (const float*)d_in[2];
    const float* min_loc     = (const float*)d_in[3];
    const float* delta       = (const float*)d_in[4];
    float* out = (float*)d_out;
    float* ws  = (float*)d_ws;

    person_loss_main<<<NBLOCK1 + 1, THREADS, 0, stream>>>(
        feature, batch_index, person_pos, min_loc, delta, ws);
    person_loss_combine<<<1, THREADS, 0, stream>>>(ws, out);
}